// Round 1
// baseline (934.931 us; speedup 1.0000x reference)
//
#include <hip/hip_runtime.h>

#define DIM 512
#define NHEADS 8
#define HD 64
#define NTOK 1024
#define NKV 256
#define MKEYS 2048

#define FMA16(ACC, A4, B4) \
  ACC[0][0] += A4.x*B4.x; ACC[0][1] += A4.x*B4.y; ACC[0][2] += A4.x*B4.z; ACC[0][3] += A4.x*B4.w; \
  ACC[1][0] += A4.y*B4.x; ACC[1][1] += A4.y*B4.y; ACC[1][2] += A4.y*B4.z; ACC[1][3] += A4.y*B4.w; \
  ACC[2][0] += A4.z*B4.x; ACC[2][1] += A4.z*B4.y; ACC[2][2] += A4.z*B4.z; ACC[2][3] += A4.z*B4.w; \
  ACC[3][0] += A4.w*B4.x; ACC[3][1] += A4.w*B4.y; ACC[3][2] += A4.w*B4.z; ACC[3][3] += A4.w*B4.w;

// sr_w (O=512, I=512, 2, 2) -> Wc[kk=seg*512+c][o]  (row-major 2048 x 512)
__global__ void build_wc_kernel(const float* __restrict__ sr_w, float* __restrict__ Wc) {
  int t = blockIdx.x * 256 + threadIdx.x;     // 2048*512 elements
  int o  = t & 511;
  int kk = t >> 9;
  int c   = kk & 511;
  int seg = kk >> 9;                          // ki*2+kj
  Wc[t] = sr_w[(size_t)o * 2048 + c * 4 + seg];
}

// P[row=b*256+i*16+j][col=seg*512+c] = x[b][(2i+ki)*32+(2j+kj)][c]
__global__ void build_patches_kernel(const float* __restrict__ x, float* __restrict__ P) {
  int t = blockIdx.x * 256 + threadIdx.x;     // float4 id, 2048*512 total
  int col4 = t & 511;
  int row  = t >> 9;
  int b = row >> 8, p = row & 255;
  int i = p >> 4, j = p & 15;
  int col = col4 * 4;
  int seg = col >> 9, c = col & 511;
  int ki = seg >> 1, kj = seg & 1;
  int n = (2 * i + ki) * 32 + (2 * j + kj);
  *(float4*)&P[(size_t)row * 2048 + col] =
      *(const float4*)&x[((size_t)b * NTOK + n) * DIM + c];
}

// C[M x N] = A[M x K] @ W[K x N] + bias, 64x64 tile, per-thread 4x4
__global__ __launch_bounds__(256) void gemm_bias_kernel(
    const float* __restrict__ A, const float* __restrict__ W,
    const float* __restrict__ bias, float* __restrict__ C,
    int M, int N, int K) {
  __shared__ float As[32][68];   // [k][row], pad to 68 (keeps 16B align, spreads banks)
  __shared__ float Ws[32][68];   // [k][col]
  const int tid = threadIdx.x;
  const int tx = tid & 15, ty = tid >> 4;
  const int row0 = blockIdx.x * 64, col0 = blockIdx.y * 64;
  float acc[4][4];
#pragma unroll
  for (int i = 0; i < 4; ++i)
#pragma unroll
    for (int j = 0; j < 4; ++j) acc[i][j] = 0.f;

  for (int k0 = 0; k0 < K; k0 += 32) {
    __syncthreads();
#pragma unroll
    for (int r = 0; r < 2; ++r) {
      int idx = tid + r * 256;                // 0..511
      int arow = idx >> 3, af4 = idx & 7;     // 64 rows x 8 float4 (BK=32)
      float4 v = *(const float4*)&A[(size_t)(row0 + arow) * K + k0 + af4 * 4];
      As[af4*4+0][arow] = v.x; As[af4*4+1][arow] = v.y;
      As[af4*4+2][arow] = v.z; As[af4*4+3][arow] = v.w;
      int wrow = idx >> 4, wf4 = idx & 15;    // 32 rows x 16 float4 (64 cols)
      *(float4*)&Ws[wrow][wf4*4] =
          *(const float4*)&W[(size_t)(k0 + wrow) * N + col0 + wf4 * 4];
    }
    __syncthreads();
#pragma unroll 8
    for (int kk = 0; kk < 32; ++kk) {
      float4 a4 = *(const float4*)&As[kk][ty * 4];
      float4 w4 = *(const float4*)&Ws[kk][tx * 4];
      FMA16(acc, a4, w4)
    }
  }
#pragma unroll
  for (int i = 0; i < 4; ++i) {
    int r = row0 + ty * 4 + i;
    float4 o;
    o.x = acc[i][0] + bias[col0 + tx*4 + 0];
    o.y = acc[i][1] + bias[col0 + tx*4 + 1];
    o.z = acc[i][2] + bias[col0 + tx*4 + 2];
    o.w = acc[i][3] + bias[col0 + tx*4 + 3];
    *(float4*)&C[(size_t)r * N + col0 + tx * 4] = o;
  }
}

// in-place LayerNorm over last dim (512), one block per row
__global__ __launch_bounds__(256) void ln_kernel(float* __restrict__ X,
                                                 const float* __restrict__ g,
                                                 const float* __restrict__ bta) {
  const int row = blockIdx.x;
  const int t = threadIdx.x;
  float2 v = *(float2*)&X[(size_t)row * DIM + t * 2];
  float s = v.x + v.y;
  float sq = v.x * v.x + v.y * v.y;
#pragma unroll
  for (int off = 1; off < 64; off <<= 1) {
    s  += __shfl_xor(s, off);
    sq += __shfl_xor(sq, off);
  }
  __shared__ float rs[4], rq[4];
  int wid = t >> 6;
  if ((t & 63) == 0) { rs[wid] = s; rq[wid] = sq; }
  __syncthreads();
  s  = rs[0] + rs[1] + rs[2] + rs[3];
  sq = rq[0] + rq[1] + rq[2] + rq[3];
  float mu  = s * (1.f / DIM);
  float var = sq * (1.f / DIM) - mu * mu;
  float inv = rsqrtf(var + 1e-5f);
  float2 gg = *(const float2*)&g[t * 2];
  float2 bb = *(const float2*)&bta[t * 2];
  float2 o;
  o.x = (v.x - mu) * inv * gg.x + bb.x;
  o.y = (v.y - mu) * inv * gg.y + bb.y;
  *(float2*)&X[(size_t)row * DIM + t * 2] = o;
}

// flash attention: grid (16 qtiles, 8 heads, 8 batch), block 256
// Q (B,1024,512) channels h*64..; keys m=(p,hh): K[m][d]=KV[b][p][hh*64+d], V at +512
__global__ __launch_bounds__(256) void attn_kernel(
    const float* __restrict__ Q, const float* __restrict__ KV,
    float* __restrict__ O) {
  __shared__ float Qs[64][64];  // [d][r]
  __shared__ float Ks[64][64];  // [d][m]
  __shared__ float Vs[64][64];  // [m][d]
  __shared__ float Ps[64][64];  // [m][r]
  const int tid = threadIdx.x;
  const int tx = tid & 15, ty = tid >> 4;
  const int qt = blockIdx.x, h = blockIdx.y, b = blockIdx.z;
  const int n0 = qt * 64;
  const float* Qb  = Q  + (size_t)b * NTOK * DIM;
  const float* KVb = KV + (size_t)b * NKV * (2 * DIM);

#pragma unroll
  for (int r2 = 0; r2 < 4; ++r2) {
    int idx = tid + r2 * 256;
    int rl = idx >> 4, f4 = idx & 15;
    float4 v = *(const float4*)&Qb[(size_t)(n0 + rl) * DIM + h * HD + f4 * 4];
    Qs[f4*4+0][rl] = v.x; Qs[f4*4+1][rl] = v.y;
    Qs[f4*4+2][rl] = v.z; Qs[f4*4+3][rl] = v.w;
  }
  float m_i[4], l_i[4], acc[4][4];
#pragma unroll
  for (int i = 0; i < 4; ++i) {
    m_i[i] = -1e30f; l_i[i] = 0.f;
#pragma unroll
    for (int j = 0; j < 4; ++j) acc[i][j] = 0.f;
  }

  for (int m0 = 0; m0 < MKEYS; m0 += 64) {
    __syncthreads();
#pragma unroll
    for (int r2 = 0; r2 < 4; ++r2) {
      int idx = tid + r2 * 256;
      int ml = idx >> 4, f4 = idx & 15;
      int mg = m0 + ml;
      const float* src = &KVb[(size_t)(mg >> 3) * 1024 + (mg & 7) * 64 + f4 * 4];
      float4 kv = *(const float4*)src;
      Ks[f4*4+0][ml] = kv.x; Ks[f4*4+1][ml] = kv.y;
      Ks[f4*4+2][ml] = kv.z; Ks[f4*4+3][ml] = kv.w;
      *(float4*)&Vs[ml][f4 * 4] = *(const float4*)(src + DIM);
    }
    __syncthreads();

    float s[4][4];
#pragma unroll
    for (int i = 0; i < 4; ++i)
#pragma unroll
      for (int j = 0; j < 4; ++j) s[i][j] = 0.f;
#pragma unroll 8
    for (int d = 0; d < 64; ++d) {
      float4 q4 = *(const float4*)&Qs[d][ty * 4];
      float4 k4 = *(const float4*)&Ks[d][tx * 4];
      FMA16(s, q4, k4)
    }
#pragma unroll
    for (int i = 0; i < 4; ++i)
#pragma unroll
      for (int j = 0; j < 4; ++j) s[i][j] *= 0.125f;

#pragma unroll
    for (int i = 0; i < 4; ++i) {
      float mx = fmaxf(fmaxf(s[i][0], s[i][1]), fmaxf(s[i][2], s[i][3]));
#pragma unroll
      for (int off = 1; off < 16; off <<= 1) mx = fmaxf(mx, __shfl_xor(mx, off));
      float mn = fmaxf(m_i[i], mx);
      float cf = __expf(m_i[i] - mn);
      float ps = 0.f;
#pragma unroll
      for (int j = 0; j < 4; ++j) {
        float pv = __expf(s[i][j] - mn);
        s[i][j] = pv;
        ps += pv;
      }
#pragma unroll
      for (int off = 1; off < 16; off <<= 1) ps += __shfl_xor(ps, off);
      l_i[i] = l_i[i] * cf + ps;
      m_i[i] = mn;
#pragma unroll
      for (int j = 0; j < 4; ++j) acc[i][j] *= cf;
    }
    // stage P transposed [m][r] (float4 over the 4 contiguous rows)
#pragma unroll
    for (int j = 0; j < 4; ++j) {
      float4 pv = make_float4(s[0][j], s[1][j], s[2][j], s[3][j]);
      *(float4*)&Ps[tx * 4 + j][ty * 4] = pv;
    }
    __syncthreads();
#pragma unroll 8
    for (int m = 0; m < 64; ++m) {
      float4 p4 = *(const float4*)&Ps[m][ty * 4];
      float4 v4 = *(const float4*)&Vs[m][tx * 4];
      FMA16(acc, p4, v4)
    }
  }

  float* Ob = O + (size_t)b * NTOK * DIM;
#pragma unroll
  for (int i = 0; i < 4; ++i) {
    float inv = 1.f / l_i[i];
    float4 o = make_float4(acc[i][0] * inv, acc[i][1] * inv,
                           acc[i][2] * inv, acc[i][3] * inv);
    *(float4*)&Ob[(size_t)(n0 + ty * 4 + i) * DIM + h * HD + tx * 4] = o;
  }
}

extern "C" void kernel_launch(void* const* d_in, const int* in_sizes, int n_in,
                              void* d_out, int out_size, void* d_ws, size_t ws_size,
                              hipStream_t stream) {
  const float* x      = (const float*)d_in[0];
  const float* q_w    = (const float*)d_in[3];
  const float* q_b    = (const float*)d_in[4];
  const float* kv_w   = (const float*)d_in[5];
  const float* kv_b   = (const float*)d_in[6];
  const float* sr_w   = (const float*)d_in[7];
  const float* sr_b   = (const float*)d_in[8];
  const float* ln_g   = (const float*)d_in[9];
  const float* ln_b   = (const float*)d_in[10];
  const float* proj_w = (const float*)d_in[11];
  const float* proj_b = (const float*)d_in[12];
  float* out = (float*)d_out;

  float* ws    = (float*)d_ws;
  float* Qbuf  = ws;                 // 8192*512
  float* Pbuf  = ws + 4194304;       // 2048*2048 patches, later reused as attn_out (8192*512)
  float* Cbuf  = ws + 8388608;       // 2048*512 conv-out, LN in place
  float* KVbuf = ws + 9437184;       // 2048*1024
  float* Wcbuf = ws + 11534336;      // 2048*512
  // total ws: 12,582,912 floats = 48 MiB

  build_wc_kernel<<<4096, 256, 0, stream>>>(sr_w, Wcbuf);
  build_patches_kernel<<<4096, 256, 0, stream>>>(x, Pbuf);
  gemm_bias_kernel<<<dim3(2048/64, 512/64), 256, 0, stream>>>(
      Pbuf, Wcbuf, sr_b, Cbuf, 2048, 512, 2048);
  ln_kernel<<<2048, 256, 0, stream>>>(Cbuf, ln_g, ln_b);
  gemm_bias_kernel<<<dim3(2048/64, 1024/64), 256, 0, stream>>>(
      Cbuf, kv_w, kv_b, KVbuf, 2048, 1024, 512);
  gemm_bias_kernel<<<dim3(8192/64, 512/64), 256, 0, stream>>>(
      x, q_w, q_b, Qbuf, 8192, 512, 512);
  attn_kernel<<<dim3(16, 8, 8), 256, 0, stream>>>(Qbuf, KVbuf, Pbuf);
  gemm_bias_kernel<<<dim3(8192/64, 512/64), 256, 0, stream>>>(
      Pbuf, proj_w, proj_b, out, 8192, 512, 512);
}

// Round 2
// 437.943 us; speedup vs baseline: 2.1348x; 2.1348x over previous
//
#include <hip/hip_runtime.h>
#include <stdint.h>

typedef __attribute__((ext_vector_type(8))) short short8;
typedef __attribute__((ext_vector_type(4))) float f32x4;

__device__ inline uint16_t f2bf(float f) {
  uint32_t u = __float_as_uint(f);
  return (uint16_t)((u + 0x7FFFu + ((u >> 16) & 1u)) >> 16);
}
__device__ inline float bf2f(uint16_t h) {
  return __uint_as_float(((uint32_t)h) << 16);
}
__device__ inline void cvt8v(const float* src, short8& hi8, short8& lo8) {
#pragma unroll
  for (int i = 0; i < 8; ++i) {
    float f = src[i];
    uint16_t h = f2bf(f);
    hi8[i] = (short)h;
    lo8[i] = (short)f2bf(f - bf2f(h));
  }
}

// ---------- prep kernels ----------

// x f32 -> xhi/xlo bf16 (8 elems/thread)
__global__ void split_x_kernel(const float* __restrict__ x, short* __restrict__ hi,
                               short* __restrict__ lo) {
  int t = blockIdx.x * 256 + threadIdx.x;   // 524288 chunks
  float buf[8];
  *(float4*)&buf[0] = *(const float4*)&x[(size_t)t * 8];
  *(float4*)&buf[4] = *(const float4*)&x[(size_t)t * 8 + 4];
  short8 h, l;
  cvt8v(buf, h, l);
  *(short8*)&hi[(size_t)t * 8] = h;
  *(short8*)&lo[(size_t)t * 8] = l;
}

// sr_w (O=512,I=512,2,2) -> WcT[o][kk=seg*512+c] split bf16
__global__ void build_wct_split(const float* __restrict__ sr_w,
                                short* __restrict__ hi, short* __restrict__ lo) {
  int t = blockIdx.x * 256 + threadIdx.x;   // 512*2048
  int kk = t & 2047, o = t >> 11;
  float v = sr_w[(size_t)o * 2048 + ((kk & 511) << 2) + (kk >> 9)];
  uint16_t h = f2bf(v);
  hi[t] = (short)h;
  lo[t] = (short)f2bf(v - bf2f(h));
}

// patches (bf16 gather from xhi/xlo): P[row=b*256+i*16+j][seg*512+c]
__global__ void build_patches_split(const short* __restrict__ xhi, const short* __restrict__ xlo,
                                    short* __restrict__ Phi, short* __restrict__ Plo) {
  int t = blockIdx.x * 256 + threadIdx.x;   // 524288 chunks of 8
  int c8 = t & 255;
  int row = t >> 8;
  int b = row >> 8, p = row & 255;
  int i = p >> 4, j = p & 15;
  int col = c8 * 8;
  int seg = col >> 9, c = col & 511;
  int ki = seg >> 1, kj = seg & 1;
  int n = (2 * i + ki) * 32 + (2 * j + kj);
  size_t src = ((size_t)b * 1024 + n) * 512 + c;
  size_t dst = (size_t)row * 2048 + col;
  *(short8*)&Phi[dst] = *(const short8*)&xhi[src];
  *(short8*)&Plo[dst] = *(const short8*)&xlo[src];
}

// f32 [K][N] -> bf16 hi/lo [N][K]
__global__ __launch_bounds__(256) void transpose_split_kernel(
    const float* __restrict__ in, short* __restrict__ ohi, short* __restrict__ olo,
    int K, int N) {
  __shared__ float tile[32][33];
  const int bx = blockIdx.x, by = blockIdx.y;
  const int tx = threadIdx.x & 31, ty = threadIdx.x >> 5;
#pragma unroll
  for (int i = 0; i < 4; ++i)
    tile[ty + i * 8][tx] = in[(size_t)(by * 32 + ty + i * 8) * N + bx * 32 + tx];
  __syncthreads();
#pragma unroll
  for (int i = 0; i < 4; ++i) {
    int n = bx * 32 + ty + i * 8;
    float v = tile[tx][ty + i * 8];
    uint16_t h = f2bf(v);
    size_t idx = (size_t)n * K + by * 32 + tx;
    ohi[idx] = (short)h;
    olo[idx] = (short)f2bf(v - bf2f(h));
  }
}

// LayerNorm over 512, inputs = Cbuf1+Cbuf2 (k-split partials), out bf16 hi/lo
__global__ __launch_bounds__(256) void ln_split_kernel(
    const float* __restrict__ X1, const float* __restrict__ X2,
    const float* __restrict__ g, const float* __restrict__ bta,
    short* __restrict__ hi, short* __restrict__ lo) {
  const int row = blockIdx.x, t = threadIdx.x;
  size_t idx = (size_t)row * 512 + t * 2;
  float2 va = *(const float2*)&X1[idx];
  float2 vb = *(const float2*)&X2[idx];
  float x0 = va.x + vb.x, x1 = va.y + vb.y;
  float s = x0 + x1, sq = x0 * x0 + x1 * x1;
#pragma unroll
  for (int off = 1; off < 64; off <<= 1) {
    s += __shfl_xor(s, off);
    sq += __shfl_xor(sq, off);
  }
  __shared__ float rs[4], rq[4];
  int wid = t >> 6;
  if ((t & 63) == 0) { rs[wid] = s; rq[wid] = sq; }
  __syncthreads();
  s = rs[0] + rs[1] + rs[2] + rs[3];
  sq = rq[0] + rq[1] + rq[2] + rq[3];
  float mu = s * (1.f / 512), var = sq * (1.f / 512) - mu * mu;
  float inv = rsqrtf(var + 1e-5f);
  float2 gg = *(const float2*)&g[t * 2], bb = *(const float2*)&bta[t * 2];
  float o0 = (x0 - mu) * inv * gg.x + bb.x;
  float o1 = (x1 - mu) * inv * gg.y + bb.y;
  uint16_t h0 = f2bf(o0), h1 = f2bf(o1);
  *(uint32_t*)&hi[idx] = (uint32_t)h0 | ((uint32_t)h1 << 16);
  uint32_t l0 = f2bf(o0 - bf2f(h0)), l1 = f2bf(o1 - bf2f(h1));
  *(uint32_t*)&lo[idx] = l0 | (l1 << 16);
}

// KV f32 [b][256][1024] K-half -> Khi/Klo [b][2048m][64d]
__global__ void build_k_split(const float* __restrict__ KV, short* __restrict__ khi,
                              short* __restrict__ klo) {
  int t = blockIdx.x * 256 + threadIdx.x;   // 8*2048*64
  int b = t >> 17, i = t & 131071;
  float v = KV[((size_t)b * 256 + (i >> 9)) * 1024 + (i & 511)];
  uint16_t h = f2bf(v);
  khi[t] = (short)h;
  klo[t] = (short)f2bf(v - bf2f(h));
}

// KV f32 V-half -> VT bf16 [b][64d][2048m]
__global__ void build_vt_kernel(const float* __restrict__ KV, short* __restrict__ vt) {
  int t = blockIdx.x * 256 + threadIdx.x;   // 8*64*2048
  int b = t >> 17, i = t & 131071;
  int d = i >> 11, m = i & 2047;
  float v = KV[((size_t)b * 256 + (m >> 3)) * 1024 + 512 + (m & 7) * 64 + d];
  vt[t] = (short)f2bf(v);
}

// ---------- bf16x3 GEMM ----------
// C[M][N] = A @ BT^T (+bias), A as hi/lo [M][lda], BT as hi/lo [N][lda]
// grid (M/128, N/128, ksplit); z-block handles k in [z*klen, (z+1)*klen), C += z*M*N
__global__ __launch_bounds__(256) void gemm_x3(
    const short* __restrict__ Ahi, const short* __restrict__ Alo,
    const short* __restrict__ BThi, const short* __restrict__ BTlo,
    const float* __restrict__ bias, float* __restrict__ C,
    int M, int N, int lda, int klen) {
  __shared__ short lds[4][4][128][8];   // [Ah,Al,Bh,Bl][kg][row][8] = 32KB
  const int tid = threadIdx.x, lane = tid & 63, wave = tid >> 6;
  const int wr = (wave >> 1) * 64, wc = (wave & 1) * 64;
  const int row0 = blockIdx.x * 128, col0 = blockIdx.y * 128;
  const int kz = blockIdx.z * klen;
  float* Cz = C + (size_t)blockIdx.z * M * N;
  const float* biasz = (blockIdx.z == 0) ? bias : nullptr;

  f32x4 acc[4][4] = {};
  const int sm = tid & 127, khalf = tid >> 7;

  for (int k0 = kz; k0 < kz + klen; k0 += 32) {
    __syncthreads();
#pragma unroll
    for (int c = 0; c < 2; ++c) {
      int kg = khalf * 2 + c;
      size_t ao = (size_t)(row0 + sm) * lda + k0 + kg * 8;
      size_t bo = (size_t)(col0 + sm) * lda + k0 + kg * 8;
      *(short8*)&lds[0][kg][sm][0] = *(const short8*)&Ahi[ao];
      *(short8*)&lds[1][kg][sm][0] = *(const short8*)&Alo[ao];
      *(short8*)&lds[2][kg][sm][0] = *(const short8*)&BThi[bo];
      *(short8*)&lds[3][kg][sm][0] = *(const short8*)&BTlo[bo];
    }
    __syncthreads();
    const int kg = lane >> 4;
    short8 ah[4], al[4], bh[4], bl[4];
#pragma unroll
    for (int i = 0; i < 4; ++i) {
      ah[i] = *(const short8*)&lds[0][kg][wr + i * 16 + (lane & 15)][0];
      al[i] = *(const short8*)&lds[1][kg][wr + i * 16 + (lane & 15)][0];
      bh[i] = *(const short8*)&lds[2][kg][wc + i * 16 + (lane & 15)][0];
      bl[i] = *(const short8*)&lds[3][kg][wc + i * 16 + (lane & 15)][0];
    }
#pragma unroll
    for (int i = 0; i < 4; ++i)
#pragma unroll
      for (int j = 0; j < 4; ++j) {
        acc[i][j] = __builtin_amdgcn_mfma_f32_16x16x32_bf16(ah[i], bh[j], acc[i][j], 0, 0, 0);
        acc[i][j] = __builtin_amdgcn_mfma_f32_16x16x32_bf16(al[i], bh[j], acc[i][j], 0, 0, 0);
        acc[i][j] = __builtin_amdgcn_mfma_f32_16x16x32_bf16(ah[i], bl[j], acc[i][j], 0, 0, 0);
      }
  }
#pragma unroll
  for (int i = 0; i < 4; ++i)
#pragma unroll
    for (int j = 0; j < 4; ++j) {
      int colb = col0 + wc + j * 16 + (lane & 15);
      float bs = biasz ? biasz[colb] : 0.f;
#pragma unroll
      for (int r = 0; r < 4; ++r) {
        int row = row0 + wr + i * 16 + (lane >> 4) * 4 + r;
        Cz[(size_t)row * N + colb] = acc[i][j][r] + bs;
      }
    }
}

// ---------- MFMA flash attention ----------
// grid (16 qtiles, 8 heads, 8 batch); Q f32 in, K split bf16, VT bf16; out bf16 hi/lo
__global__ __launch_bounds__(256) void attn_kernel(
    const float* __restrict__ Q, const short* __restrict__ Khi,
    const short* __restrict__ Klo, const short* __restrict__ VT,
    short* __restrict__ Ohi, short* __restrict__ Olo) {
  __shared__ short kls[2][8][64][8];   // [hi/lo][dg][m][8d] 16KB
  __shared__ short Psh[4][1024];       // per-wave P hi, [q16][m64] XOR-swizzled, 8KB
  __shared__ short Psl[4][1024];       // 8KB
  const int tid = threadIdx.x, lane = tid & 63, wave = tid >> 6;
  const int qt = blockIdx.x, h = blockIdx.y, b = blockIdx.z;
  const int n0 = qt * 64;

  // Q frags -> regs (hi/lo), wave's 16 rows
  short8 qh[2], ql[2];
  {
    const float* Qb = Q + ((size_t)b * 1024 + n0 + wave * 16 + (lane & 15)) * 512 + h * 64;
#pragma unroll
    for (int ks = 0; ks < 2; ++ks) {
      int dg = ks * 4 + (lane >> 4);
      float buf[8];
      *(float4*)&buf[0] = *(const float4*)(Qb + dg * 8);
      *(float4*)&buf[4] = *(const float4*)(Qb + dg * 8 + 4);
      cvt8v(buf, qh[ks], ql[ks]);
    }
  }
  float m_i[4] = {-1e30f, -1e30f, -1e30f, -1e30f};
  float l_i[4] = {0.f, 0.f, 0.f, 0.f};
  f32x4 oacc[4] = {};

  const short* Kh = Khi + (size_t)b * 2048 * 64;
  const short* Kl = Klo + (size_t)b * 2048 * 64;
  const short* Vb = VT + (size_t)b * 64 * 2048;

  for (int t = 0; t < 32; ++t) {
    const int m0 = t * 64;
    __syncthreads();
    {   // stage K hi/lo
      int mm = tid & 63, dg0 = tid >> 6;
#pragma unroll
      for (int c = 0; c < 2; ++c) {
        int dg = dg0 + c * 4;
        size_t off = (size_t)(m0 + mm) * 64 + dg * 8;
        *(short8*)&kls[0][dg][mm][0] = *(const short8*)&Kh[off];
        *(short8*)&kls[1][dg][mm][0] = *(const short8*)&Kl[off];
      }
    }
    __syncthreads();
    // QK^T (x3 split)
    f32x4 s[4] = {};
#pragma unroll
    for (int ks = 0; ks < 2; ++ks) {
      int dg = ks * 4 + (lane >> 4);
#pragma unroll
      for (int nf = 0; nf < 4; ++nf) {
        short8 kh8 = *(const short8*)&kls[0][dg][nf * 16 + (lane & 15)][0];
        short8 kl8 = *(const short8*)&kls[1][dg][nf * 16 + (lane & 15)][0];
        s[nf] = __builtin_amdgcn_mfma_f32_16x16x32_bf16(qh[ks], kh8, s[nf], 0, 0, 0);
        s[nf] = __builtin_amdgcn_mfma_f32_16x16x32_bf16(ql[ks], kh8, s[nf], 0, 0, 0);
        s[nf] = __builtin_amdgcn_mfma_f32_16x16x32_bf16(qh[ks], kl8, s[nf], 0, 0, 0);
      }
    }
    // online softmax (rows q = (lane>>4)*4 + r, cols across 16-lane group)
#pragma unroll
    for (int r = 0; r < 4; ++r) {
      float mx = fmaxf(fmaxf(s[0][r], s[1][r]), fmaxf(s[2][r], s[3][r]));
#pragma unroll
      for (int off = 1; off < 16; off <<= 1) mx = fmaxf(mx, __shfl_xor(mx, off));
      mx *= 0.125f;
      float mn = fmaxf(m_i[r], mx);
      float cf = __expf(m_i[r] - mn);
      m_i[r] = mn;
      float ps = 0.f;
#pragma unroll
      for (int nf = 0; nf < 4; ++nf) {
        float pv = __expf(s[nf][r] * 0.125f - mn);
        s[nf][r] = pv;
        ps += pv;
      }
#pragma unroll
      for (int off = 1; off < 16; off <<= 1) ps += __shfl_xor(ps, off);
      l_i[r] = l_i[r] * cf + ps;
#pragma unroll
      for (int df = 0; df < 4; ++df) oacc[df][r] *= cf;
    }
    // P -> LDS (bf16 hi/lo, swizzled), per-wave region (no barrier needed)
#pragma unroll
    for (int nf = 0; nf < 4; ++nf)
#pragma unroll
      for (int r = 0; r < 4; ++r) {
        int q = (lane >> 4) * 4 + r, m = nf * 16 + (lane & 15);
        float pv = s[nf][r];
        uint16_t ph = f2bf(pv);
        int sidx = q * 64 + (m ^ ((q & 7) << 3));
        Psh[wave][sidx] = (short)ph;
        Psl[wave][sidx] = (short)f2bf(pv - bf2f(ph));
      }
    // PV (P hi+lo, V single bf16 direct from L2)
#pragma unroll
    for (int ks = 0; ks < 2; ++ks) {
      int q = lane & 15, mc = ks * 4 + (lane >> 4);
      int pidx = q * 64 + ((mc ^ (q & 7)) << 3);
      short8 pa = *(const short8*)&Psh[wave][pidx];
      short8 pl = *(const short8*)&Psl[wave][pidx];
#pragma unroll
      for (int df = 0; df < 4; ++df) {
        short8 vb8 = *(const short8*)&Vb[(size_t)(df * 16 + (lane & 15)) * 2048 + m0 + mc * 8];
        oacc[df] = __builtin_amdgcn_mfma_f32_16x16x32_bf16(pa, vb8, oacc[df], 0, 0, 0);
        oacc[df] = __builtin_amdgcn_mfma_f32_16x16x32_bf16(pl, vb8, oacc[df], 0, 0, 0);
      }
    }
  }
  // epilogue -> bf16 hi/lo (feeds proj GEMM)
  size_t obase = ((size_t)b * 1024 + n0 + wave * 16) * 512 + h * 64;
#pragma unroll
  for (int df = 0; df < 4; ++df) {
    float rl[4];
#pragma unroll
    for (int r = 0; r < 4; ++r) rl[r] = 1.f / l_i[r];
#pragma unroll
    for (int r = 0; r < 4; ++r) {
      int q = (lane >> 4) * 4 + r, d = df * 16 + (lane & 15);
      float ov = oacc[df][r] * rl[r];
      uint16_t hh = f2bf(ov);
      size_t idx = obase + (size_t)q * 512 + d;
      Ohi[idx] = (short)hh;
      Olo[idx] = (short)f2bf(ov - bf2f(hh));
    }
  }
}

// ---------- launcher ----------
extern "C" void kernel_launch(void* const* d_in, const int* in_sizes, int n_in,
                              void* d_out, int out_size, void* d_ws, size_t ws_size,
                              hipStream_t stream) {
  const float* x      = (const float*)d_in[0];
  const float* q_w    = (const float*)d_in[3];
  const float* q_b    = (const float*)d_in[4];
  const float* kv_w   = (const float*)d_in[5];
  const float* kv_b   = (const float*)d_in[6];
  const float* sr_w   = (const float*)d_in[7];
  const float* sr_b   = (const float*)d_in[8];
  const float* ln_g   = (const float*)d_in[9];
  const float* ln_b   = (const float*)d_in[10];
  const float* proj_w = (const float*)d_in[11];
  const float* proj_b = (const float*)d_in[12];

  char* W = (char*)d_ws;
  const size_t MB = 1024 * 1024;
  short* xhi   = (short*)(W);                 // 8MB   region A
  short* xlo   = (short*)(W + 8 * MB);        // 8MB
  short* Phi   = (short*)(W + 16 * MB);       // 8MB   region B
  short* Plo   = (short*)(W + 24 * MB);       // 8MB
  float* KVbuf = (float*)(W + 16 * MB);       // 8MB   (B reuse)
  float* Qbuf  = (float*)(W + 16 * MB);       // 16MB  (B reuse)
  short* WcThi = (short*)(W + 32 * MB);       // 2MB   region C
  short* WcTlo = (short*)(W + 34 * MB);       // 2MB
  short* LNhi  = (short*)(W + 32 * MB);       // (C reuse)
  short* LNlo  = (short*)(W + 34 * MB);
  float* Cbuf  = (float*)(W + 36 * MB);       // 8MB   region D (2 k-split halves)
  short* Khi   = (short*)(W + 36 * MB);       // (D reuse) 2MB
  short* Klo   = (short*)(W + 38 * MB);       // 2MB
  short* VTb   = (short*)(W + 44 * MB);       // 2MB   region F
  short* wThi  = (short*)(W + 46 * MB);       // 1MB   region G (shared by 3 transposes)
  short* wTlo  = (short*)(W + 47 * MB);       // 1MB
  short* Ohi   = (short*)(W);                 // (A reuse)
  short* Olo   = (short*)(W + 8 * MB);

  split_x_kernel<<<2048, 256, 0, stream>>>(x, xhi, xlo);
  build_wct_split<<<4096, 256, 0, stream>>>(sr_w, WcThi, WcTlo);
  build_patches_split<<<2048, 256, 0, stream>>>(xhi, xlo, Phi, Plo);
  gemm_x3<<<dim3(16, 4, 2), 256, 0, stream>>>(Phi, Plo, WcThi, WcTlo, sr_b, Cbuf,
                                              2048, 512, 2048, 1024);
  ln_split_kernel<<<2048, 256, 0, stream>>>(Cbuf, Cbuf + (size_t)2048 * 512, ln_g, ln_b,
                                            LNhi, LNlo);
  transpose_split_kernel<<<dim3(32, 16), 256, 0, stream>>>(kv_w, wThi, wTlo, 512, 1024);
  gemm_x3<<<dim3(16, 8, 1), 256, 0, stream>>>(LNhi, LNlo, wThi, wTlo, kv_b, KVbuf,
                                              2048, 1024, 512, 512);
  build_k_split<<<4096, 256, 0, stream>>>(KVbuf, Khi, Klo);
  build_vt_kernel<<<4096, 256, 0, stream>>>(KVbuf, VTb);
  transpose_split_kernel<<<dim3(16, 16), 256, 0, stream>>>(q_w, wThi, wTlo, 512, 512);
  gemm_x3<<<dim3(64, 4, 1), 256, 0, stream>>>(xhi, xlo, wThi, wTlo, q_b, Qbuf,
                                              8192, 512, 512, 512);
  attn_kernel<<<dim3(16, 8, 8), 256, 0, stream>>>(Qbuf, Khi, Klo, VTb, Ohi, Olo);
  transpose_split_kernel<<<dim3(16, 16), 256, 0, stream>>>(proj_w, wThi, wTlo, 512, 512);
  gemm_x3<<<dim3(64, 4, 1), 256, 0, stream>>>(Ohi, Olo, wThi, wTlo, proj_b,
                                              (float*)d_out, 8192, 512, 512, 512);
}